// Round 8
// baseline (231.223 us; speedup 1.0000x reference)
//
#include <hip/hip_runtime.h>
#include <hip/hip_bf16.h>
#include <stdint.h>

// ---------------------------------------------------------------------------
// GQA attention block, MI355X/gfx950, bf16 MFMA pipeline.
//   B=8 T=512 C=2048 H=16 KVH=4 D=128
// Round 8: qkv back to 2-phase 128^2 @3/CU (round-6 winner) with A-operand
// loaded DIRECTLY global->registers (VMEM pipe), only B through LDS.
// Rationale: round-6 core was LDS-BW-bound (96 KB LDS traffic per
// block-K-tile = ~168 B/cyc > 128 B/cyc peak). A-direct halves LDS traffic.
// out/attn/prep/rope identical to round 6.
// ---------------------------------------------------------------------------

typedef __bf16 bf16x8 __attribute__((ext_vector_type(8)));
typedef float  f32x4  __attribute__((ext_vector_type(4)));
typedef float  f4     __attribute__((ext_vector_type(4)));
typedef unsigned short u16x8 __attribute__((ext_vector_type(8)));
typedef unsigned short u16x4 __attribute__((ext_vector_type(4)));
typedef unsigned short us;

template<int V> struct Ic { static constexpr int v = V; };

__device__ __forceinline__ float bf2f(us u) {
  unsigned int x = ((unsigned int)u) << 16;
  return __builtin_bit_cast(float, x);
}
__device__ __forceinline__ us f2bf(float f) {   // round-to-nearest-even
  unsigned int x = __builtin_bit_cast(unsigned int, f);
  unsigned int r = x + 0x7fffu + ((x >> 16) & 1u);
  return (us)(r >> 16);
}

// async global->LDS, 16B per lane; LDS dest must be linear (uniform + lane*16)
__device__ __forceinline__ void gload16(const void* gsrc, void* ldst) {
  auto g = (const __attribute__((address_space(1))) void*)gsrc;
  auto l = (__attribute__((address_space(3))) void*)ldst;
  __builtin_amdgcn_global_load_lds(g, l, 16, 0, 0);
}

#define BAR() __builtin_amdgcn_s_barrier()
#define LGK0() do { asm volatile("s_waitcnt lgkmcnt(0)" ::: "memory"); \
                    __builtin_amdgcn_sched_barrier(0); } while (0)

template<int N> __device__ __forceinline__ void VMW() {
  if constexpr (N == 0)      asm volatile("s_waitcnt vmcnt(0)" ::: "memory");
  else if constexpr (N == 2) asm volatile("s_waitcnt vmcnt(2)" ::: "memory");
  else if constexpr (N == 3) asm volatile("s_waitcnt vmcnt(3)" ::: "memory");
  else if constexpr (N == 4) asm volatile("s_waitcnt vmcnt(4)" ::: "memory");
  else static_assert(N == 0 || N == 2 || N == 3 || N == 4, "unsupported vmcnt");
  __builtin_amdgcn_sched_barrier(0);
}

// ---------------------------------------------------------------------------
// merged prep kernel: grid 6784 x 256
// ---------------------------------------------------------------------------
__global__ __launch_bounds__(256) void prep_kernel(
    const float* __restrict__ x, const float* __restrict__ wq,
    const float* __restrict__ wk, const float* __restrict__ wv,
    const float* __restrict__ wo, us* __restrict__ xb,
    us* __restrict__ wcat, us* __restrict__ wot,
    float* __restrict__ ct, float* __restrict__ st) {
  const int bid = blockIdx.x, tid = threadIdx.x;
  if (bid < 4096) {
    size_t idx = (size_t)bid * 256 + tid;
    const f4* p = (const f4*)(x + idx * 8);
    f4 a = p[0], b = p[1];
    u16x8 o;
#pragma unroll
    for (int e = 0; e < 4; ++e) { o[e] = f2bf(a[e]); o[4 + e] = f2bf(b[e]); }
    *(u16x8*)(xb + idx * 8) = o;
  } else if (bid < 6656) {
    __shared__ float lds[64][65];
    int lb = bid - 4096;              // 0..2559
    int bx = lb % 80, ky = lb / 80;   // ky 0..31
    const float* src; us* dst; int N, rowOff, nb;
    if (bx < 32)      { src = wq; dst = wcat; N = 2048; rowOff = 0;    nb = bx; }
    else if (bx < 40) { src = wk; dst = wcat; N = 512;  rowOff = 2048; nb = bx - 32; }
    else if (bx < 48) { src = wv; dst = wcat; N = 512;  rowOff = 2560; nb = bx - 40; }
    else              { src = wo; dst = wot;  N = 2048; rowOff = 0;    nb = bx - 48; }
    const int n0 = nb * 64, k0 = ky * 64;
    const int c = tid & 63, rq = tid >> 6;
#pragma unroll
    for (int i = 0; i < 16; ++i) {
      int r = i * 4 + rq;
      lds[r][c] = src[(size_t)(k0 + r) * N + n0 + c];
    }
    __syncthreads();
#pragma unroll
    for (int i = 0; i < 16; ++i) {
      int nr = i * 4 + rq;
      dst[(size_t)(rowOff + n0 + nr) * 2048 + k0 + c] = f2bf(lds[c][nr]);
    }
  } else {
    int idx = (bid - 6656) * 256 + tid;   // 0..32767
    int i = idx & 63, t = idx >> 6;
    float inv = exp2f(-(float)i * (13.287712379549449f / 64.0f));
    float ang = (float)t * inv;
    ct[idx] = cosf(ang);
    st[idx] = sinf(ang);
  }
}

// in-place RoPE on Kh [32][512][128] only (Q roped in attn). grid 1024.
__global__ void rope_k_kernel(us* __restrict__ Kh,
                              const float* __restrict__ ct, const float* __restrict__ st) {
  int idx = blockIdx.x * 256 + threadIdx.x;   // 262,144 exact
  int dq = idx & 15;
  int t = (idx >> 4) & 511;
  int slot = idx >> 13;                       // 0..31
  us* rowp = Kh + ((size_t)slot * 512 + t) * 128;
  int d0 = dq * 4;
  u16x4 x1 = *(const u16x4*)(rowp + d0);
  u16x4 x2 = *(const u16x4*)(rowp + 64 + d0);
  f4 c = *(const f4*)(ct + t * 64 + d0);
  f4 s = *(const f4*)(st + t * 64 + d0);
  u16x4 o1, o2;
#pragma unroll
  for (int e = 0; e < 4; ++e) {
    float a = bf2f(x1[e]), b = bf2f(x2[e]);
    o1[e] = f2bf(a * c[e] - b * s[e]);
    o2[e] = f2bf(b * c[e] + a * s[e]);
  }
  *(u16x4*)(rowp + d0) = o1;
  *(u16x4*)(rowp + 64 + d0) = o2;
}

// ---------------------------------------------------------------------------
// 2-phase 128x128 GEMM core, A-DIRECT variant: A fragments loaded straight
// from global (L2-resident panel) into registers; only B staged in LDS
// (async gload16, XOR-swizzled). Halves LDS traffic vs both-operand staging.
// ---------------------------------------------------------------------------
__device__ __forceinline__ void gemm2ad_core(const us* __restrict__ A,
    const us* __restrict__ Bt, const int K, const int m0, const int n0,
    us* BT, f32x4 (&acc)[4][4]) {
  const int tid = threadIdx.x;
  const int lane = tid & 63;
  const int wid = tid >> 6;
  const int wm = wid >> 1, wn = wid & 1;
  const int lr = lane & 15, lq = lane >> 4;
  const f32x4 zz = {0.f, 0.f, 0.f, 0.f};
#pragma unroll
  for (int i = 0; i < 4; ++i)
#pragma unroll
    for (int j = 0; j < 4; ++j) acc[i][j] = zz;

  // per-fragment A row base pointers (row = m0 + wm*64 + i*16 + lr)
  const us* Ar[4];
#pragma unroll
  for (int i = 0; i < 4; ++i)
    Ar[i] = A + (size_t)(m0 + wm * 64 + i * 16 + lr) * K + (lq << 3);

  const int KT = K >> 6;
  for (int kt = 0; kt < KT; ++kt) {
    __syncthreads();
    // stage B tile [128 rows][64 k] via async LDS, source pre-swizzled
#pragma unroll
    for (int i = 0; i < 4; ++i) {
      int c = i * 256 + tid;
      int row = c >> 3, kc = (c & 7) ^ (row & 7);
      gload16(Bt + (size_t)(n0 + row) * K + (kt << 6) + (kc << 3), BT + c * 8);
    }
    // A fragments: 8 x global_load_dwordx4 (VMEM pipe; L2-resident panel)
    bf16x8 af[4][2];
#pragma unroll
    for (int i = 0; i < 4; ++i)
#pragma unroll
      for (int ks = 0; ks < 2; ++ks)
        af[i][ks] = *(const bf16x8*)(Ar[i] + (kt << 6) + (ks << 5));
    __syncthreads();   // compiler drains vmcnt here (B in LDS, A in regs)
#pragma unroll
    for (int ks = 0; ks < 2; ++ks) {
      bf16x8 bfm[4];
#pragma unroll
      for (int j = 0; j < 4; ++j) {
        int R = wn * 64 + j * 16 + lr;
        bfm[j] = *(const bf16x8*)((const char*)BT + R * 128 +
                                  ((ks * 64 + lq * 16) ^ ((R & 7) << 4)));
      }
#pragma unroll
      for (int i = 0; i < 4; ++i)
#pragma unroll
        for (int j = 0; j < 4; ++j)
          acc[i][j] = __builtin_amdgcn_mfma_f32_16x16x32_bf16(af[i][ks], bfm[j], acc[i][j], 0, 0, 0);
    }
  }
}

// QKV GEMM: xb [4096][2048] @ wcat [3072][2048]^T; Q,K scattered per-head,
// V scattered directly transposed into Vt [32][128][512].
// XCD chunk = 4 m-tiles x 24 n-tiles: A panels (2 MB) stay L2-resident.
__global__ __launch_bounds__(256, 4) void gemm_qkv2_kernel(const us* __restrict__ xb,
    const us* __restrict__ wcat, us* __restrict__ Qh, us* __restrict__ Kh,
    us* __restrict__ Vt) {
  __shared__ __align__(16) us BT[128 * 64];       // 16 KiB (A not staged)
  const int bid = blockIdx.x;                     // 768 = 8 XCD * 96
  const int xcd = bid & 7, c = bid >> 3;          // c in [0,96)
  const int m0 = (xcd * 4 + c / 24) << 7;         // 4 A-panels per XCD
  const int n0 = (c % 24) << 7;                   // n fastest: 24 co-resident
  f32x4 acc[4][4];
  gemm2ad_core(xb, wcat, 2048, m0, n0, BT, acc);

  const int tid = threadIdx.x, lane = tid & 63, wid = tid >> 6;
  const int wm = wid >> 1, wn = wid & 1, lr = lane & 15, lq = lane >> 4;
#pragma unroll
  for (int i = 0; i < 4; ++i)
#pragma unroll
    for (int j = 0; j < 4; ++j) {
      int col = n0 + wn * 64 + j * 16 + lr;
#pragma unroll
      for (int r = 0; r < 4; ++r) {
        int row = m0 + wm * 64 + i * 16 + lq * 4 + r;
        int bb = row >> 9, t = row & 511;
        us val = f2bf(acc[i][j][r]);
        if (col < 2048) {
          Qh[((size_t)(bb * 16 + (col >> 7)) * 512 + t) * 128 + (col & 127)] = val;
        } else if (col < 2560) {
          int cc = col - 2048;
          Kh[((size_t)(bb * 4 + (cc >> 7)) * 512 + t) * 128 + (cc & 127)] = val;
        } else {
          int cc = col - 2560;
          Vt[((size_t)(bb * 4 + (cc >> 7)) * 128 + (cc & 127)) * 512 + t] = val;
        }
      }
    }
}

// ---------------------------------------------------------------------------
// 8-phase counted-vmcnt GEMM core (round-5/6 version): out-GEMM only.
// ---------------------------------------------------------------------------
template<int BM, int BN, int WM, int WN>
__device__ __forceinline__ void gemm8_core(const us* __restrict__ A,
    const us* __restrict__ Bt, const int K, const int m0, const int n0,
    us* sm, f32x4 (&acc)[BM / (16 * WM)][BN / (16 * WN)]) {
  constexpr int MF = BM / (16 * WM), NF = BN / (16 * WN);
  constexpr int MH = MF / 2, NH = NF / 2;
  constexpr int QM = MH * 16, QN = NH * 16;     // per-wave quarter rows
  constexpr int AHALF = (BM / 2) * 64, ABUF = BM * 64, ALDS = 2 * ABUF;
  constexpr int BHALF = (BN / 2) * 64, BBUF = BN * 64;
  constexpr int AL = BM / 128, BL = BN / 128;   // gloads/thread per half
  const int tid = threadIdx.x, lane = tid & 63, wid = tid >> 6;
  const int wm = wid / WN, wn = wid % WN;
  const int lr = lane & 15, lq = lane >> 4;

  const f32x4 zz = {0.f, 0.f, 0.f, 0.f};
#pragma unroll
  for (int i = 0; i < MF; ++i)
#pragma unroll
    for (int j = 0; j < NF; ++j) acc[i][j] = zz;

  bf16x8 afr[MH][2], bfr[NH][2];

  auto stageA = [&](int kt, int qd, int h) {
#pragma unroll
    for (int i = 0; i < AL; ++i) {
      int c = i * 512 + tid;
      int lrow = c >> 3;
      int grow = (lrow / QM) * (2 * QM) + h * QM + (lrow % QM);
      int kcs = (c & 7) ^ (lrow & 7);
      gload16(A + (size_t)(m0 + grow) * K + (kt << 6) + (kcs << 3),
              sm + qd * ABUF + h * AHALF + c * 8);
    }
  };
  auto stageB = [&](int kt, int qd, int h) {
#pragma unroll
    for (int i = 0; i < BL; ++i) {
      int c = i * 512 + tid;
      int lrow = c >> 3;
      int grow = (lrow / QN) * (2 * QN) + h * QN + (lrow % QN);
      int kcs = (c & 7) ^ (lrow & 7);
      gload16(Bt + (size_t)(n0 + grow) * K + (kt << 6) + (kcs << 3),
              sm + ALDS + qd * BBUF + h * BHALF + c * 8);
    }
  };
  auto lda = [&](int q, int h) {
#pragma unroll
    for (int f = 0; f < MH; ++f) {
      int R = wm * QM + f * 16 + lr;
      const char* base = (const char*)(sm + q * ABUF + h * AHALF + R * 64);
      int sw = (R & 7) << 4;
#pragma unroll
      for (int ks = 0; ks < 2; ++ks)
        afr[f][ks] = *(const bf16x8*)(base + ((ks * 64 + lq * 16) ^ sw));
    }
  };
  auto ldb = [&](int q, int h) {
#pragma unroll
    for (int g = 0; g < NH; ++g) {
      int R = wn * QN + g * 16 + lr;
      const char* base = (const char*)(sm + ALDS + q * BBUF + h * BHALF + R * 64);
      int sw = (R & 7) << 4;
#pragma unroll
      for (int ks = 0; ks < 2; ++ks)
        bfr[g][ks] = *(const bf16x8*)(base + ((ks * 64 + lq * 16) ^ sw));
    }
  };
  auto mmac = [&](auto MQ, auto NQ) {
    constexpr int mq = decltype(MQ)::v, nq = decltype(NQ)::v;
    __builtin_amdgcn_s_setprio(1);
#pragma unroll
    for (int ks = 0; ks < 2; ++ks)
#pragma unroll
      for (int f = 0; f < MH; ++f)
#pragma unroll
        for (int g = 0; g < NH; ++g)
          acc[mq * MH + f][nq * NH + g] = __builtin_amdgcn_mfma_f32_16x16x32_bf16(
              afr[f][ks], bfr[g][ks], acc[mq * MH + f][nq * NH + g], 0, 0, 0);
    __builtin_amdgcn_s_setprio(0);
  };

  // prologue: tile 0 -> buf 0, issue order = consumption order
  stageA(0, 0, 0); stageB(0, 0, 0); stageB(0, 0, 1); stageA(0, 0, 1);
  VMW<AL + BL>(); BAR();

  const int NT = K >> 6;
  for (int kt = 0; kt < NT; ++kt) {
    const int q = kt & 1, qn = q ^ 1;
    const bool pf = (kt + 1 < NT);
    // ---- ph1: quadrant (0,0); reads Ah0,Bh0 ----
    lda(q, 0); ldb(q, 0);
    if (pf) stageA(kt + 1, qn, 0);
    BAR(); LGK0(); mmac(Ic<0>{}, Ic<0>{});
    if (pf) VMW<2 * AL>(); else VMW<AL>();       // next: Bh1(kt)
    BAR();
    // ---- ph2: quadrant (0,1); reads Bh1 ----
    ldb(q, 1);
    if (pf) stageB(kt + 1, qn, 0);
    BAR(); LGK0(); mmac(Ic<0>{}, Ic<1>{});
    if (pf) VMW<AL + BL>(); else VMW<0>();       // next: Ah1(kt)
    BAR();
    // ---- ph3: quadrant (1,1); reads Ah1 ----
    lda(q, 1);
    if (pf) stageB(kt + 1, qn, 1);
    BAR(); LGK0(); mmac(Ic<1>{}, Ic<1>{});
    BAR();                                        // ph4 needs nothing new
    // ---- ph4: quadrant (1,0); re-reads Bh0 ----
    ldb(q, 0);
    if (pf) stageA(kt + 1, qn, 1);
    BAR(); LGK0(); mmac(Ic<1>{}, Ic<0>{});
    if (pf) VMW<AL + BL>();                      // next tile: Ah0,Bh0(kt+1)
    BAR();
  }
}

// output GEMM: Oh [4096][2048] @ wot [2048][2048]^T -> fp32 out, 256x128 tiles
// XCD chunk = 2 m-tiles x 16 n-tiles: A panels (2 MB) L2-resident, B streamed.
__global__ __launch_bounds__(512, 2) void gemm_out8_kernel(const us* __restrict__ Ob,
    const us* __restrict__ wot, float* __restrict__ out) {
  __shared__ __align__(16) us sm[49152];          // 96 KiB
  const int bid = blockIdx.x;                     // 256 = 8 XCD * 32
  const int xcd = bid & 7, c = bid >> 3;          // c in [0,32)
  const int m0 = (xcd * 2 + (c >> 4)) << 8;       // 2 A-panels per XCD
  const int n0 = (c & 15) << 7;                   // n fastest: 16 co-resident
  f32x4 acc[8][2];
  gemm8_core<256, 128, 2, 4>(Ob, wot, 2048, m0, n0, sm, acc);

  const int tid = threadIdx.x, lane = tid & 63, wid = tid >> 6;
  const int wm = wid >> 2, wn = wid & 3, lr = lane & 15, lq = lane >> 4;
#pragma unroll
  for (int f = 0; f < 8; ++f)
#pragma unroll
    for (int g = 0; g < 2; ++g) {
      int col = n0 + wn * 32 + g * 16 + lr;
#pragma unroll
      for (int r = 0; r < 4; ++r) {
        int row = m0 + wm * 128 + f * 16 + lq * 4 + r;
        out[(size_t)row * 2048 + col] = acc[f][g][r];
      }
    }
}

// ---------------------------------------------------------------------------
// flash attention, in-register Q-RoPE+scale. 1D grid 1024:
//   xcd = batch b (K/V + Q L2-resident), qb reversed (LPT).
// ---------------------------------------------------------------------------
__global__ __launch_bounds__(256) void attn_kernel(const us* __restrict__ Qh,
    const us* __restrict__ Kh, const us* __restrict__ Vt, us* __restrict__ Oh,
    const float* __restrict__ ct, const float* __restrict__ st) {
  __shared__ __align__(16) us Ktile[64 * 128];
  __shared__ __align__(16) us Vtile[128 * 64];
  __shared__ __align__(16) us Plds[4 * 16 * 72];
  const int tid = threadIdx.x, lane = tid & 63, w = tid >> 6;
  const int lr = lane & 15, lq = lane >> 4;
  const int bid = blockIdx.x;            // 1024 = 8 XCD(=batch) * 128
  const int b = bid & 7, cc_ = bid >> 3; // cc_ in [0,128)
  const int h = cc_ & 15, qb = 7 - (cc_ >> 4);
  const int bh = b * 16 + h, kvh = h >> 2;
  const us* Kbh = Kh + (size_t)(b * 4 + kvh) * 512 * 128;
  const us* Vbh = Vt + (size_t)(b * 4 + kvh) * 128 * 512;

  // Q fragments with in-register RoPE + 1/sqrt(128) scale.
  const int t_abs = qb * 64 + w * 16 + lr;
  const us* Qrow = Qh + ((size_t)bh * 512 + t_abs) * 128;
  bf16x8 qf[4];
  {
    const float* cp = ct + t_abs * 64 + (lq << 3);
    const float* sp = st + t_abs * 64 + (lq << 3);
#pragma unroll
    for (int ks = 0; ks < 2; ++ks) {
      u16x8 a = *(const u16x8*)(Qrow + ks * 32 + (lq << 3));
      u16x8 bb2 = *(const u16x8*)(Qrow + 64 + ks * 32 + (lq << 3));
      u16x8 oa, ob;
#pragma unroll
      for (int e = 0; e < 8; ++e) {
        float c = cp[ks * 32 + e], s = sp[ks * 32 + e];
        float av = bf2f(a[e]), bv = bf2f(bb2[e]);
        oa[e] = f2bf((av * c - bv * s) * 0.08838834764831845f);
        ob[e] = f2bf((bv * c + av * s) * 0.08838834764831845f);
      }
      qf[ks] = __builtin_bit_cast(bf16x8, oa);
      qf[ks + 2] = __builtin_bit_cast(bf16x8, ob);
    }
  }

  const f32x4 zz = {0.f, 0.f, 0.f, 0.f};
  f32x4 o[8];
#pragma unroll
  for (int i = 0; i < 8; ++i) o[i] = zz;
  float m[4], ll[4];
#pragma unroll
  for (int r = 0; r < 4; ++r) { m[r] = -1e30f; ll[r] = 0.f; }
  us* Pw = Plds + w * 16 * 72;

  for (int j = 0; j <= qb; ++j) {
    __syncthreads();
#pragma unroll
    for (int it = 0; it < 4; ++it) {
      int c = it * 256 + tid;
      int row = c >> 4, kc = c & 15;
      gload16(Kbh + (size_t)(j * 64 + row) * 128 + ((kc ^ (row & 7)) << 3),
              Ktile + (c << 3));
    }
#pragma unroll
    for (int it = 0; it < 4; ++it) {
      int c = it * 256 + tid;
      int row = c >> 3, tc = c & 7;
      gload16(Vbh + (size_t)row * 512 + j * 64 + ((tc ^ (row & 7)) << 3),
              Vtile + (c << 3));
    }
    __syncthreads();

    f32x4 s[4];
#pragma unroll
    for (int nb = 0; nb < 4; ++nb) s[nb] = zz;
#pragma unroll
    for (int ks = 0; ks < 4; ++ks) {
#pragma unroll
      for (int nb = 0; nb < 4; ++nb) {
        int row = nb * 16 + lr;
        bf16x8 kf = *(const bf16x8*)(Ktile + (row << 7) + (((ks * 4 + lq) ^ (row & 7)) << 3));
        s[nb] = __builtin_amdgcn_mfma_f32_16x16x32_bf16(qf[ks], kf, s[nb], 0, 0, 0);
      }
    }
    if (j == qb) {
#pragma unroll
      for (int nb = 0; nb < 4; ++nb)
#pragma unroll
        for (int r = 0; r < 4; ++r)
          if (nb * 16 + lr > w * 16 + lq * 4 + r) s[nb][r] = -1e30f;
    }

    float tm[4], alpha[4], rs[4];
#pragma unroll
    for (int r = 0; r < 4; ++r)
      tm[r] = fmaxf(fmaxf(s[0][r], s[1][r]), fmaxf(s[2][r], s[3][r]));
#pragma unroll
    for (int off = 1; off < 16; off <<= 1)
#pragma unroll
      for (int r = 0; r < 4; ++r)
        tm[r] = fmaxf(tm[r], __shfl_xor(tm[r], off, 64));
#pragma unroll
    for (int r = 0; r < 4; ++r) {
      float mn = fmaxf(m[r], tm[r]);
      alpha[r] = __expf(m[r] - mn);
      m[r] = mn;
    }
#pragma unroll
    for (int nb = 0; nb < 4; ++nb)
#pragma unroll
      for (int r = 0; r < 4; ++r)
        s[nb][r] = __expf(s[nb][r] - m[r]);
#pragma unroll
    for (int r = 0; r < 4; ++r)
      rs[r] = s[0][r] + s[1][r] + s[2][r] + s[3][r];
#pragma unroll
    for (int off = 1; off < 16; off <<= 1)
#pragma unroll
      for (int r = 0; r < 4; ++r)
        rs[r] += __shfl_xor(rs[r], off, 64);
#pragma unroll
    for (int r = 0; r < 4; ++r) ll[r] = ll[r] * alpha[r] + rs[r];
#pragma unroll
    for (int i = 0; i < 8; ++i)
#pragma unroll
      for (int r = 0; r < 4; ++r) o[i][r] *= alpha[r];

#pragma unroll
    for (int nb = 0; nb < 4; ++nb)
#pragma unroll
      for (int r = 0; r < 4; ++r)
        Pw[(lq * 4 + r) * 72 + nb * 16 + lr] = f2bf(s[nb][r]);

#pragma unroll
    for (int ks2 = 0; ks2 < 2; ++ks2) {
      bf16x8 pf = *(const bf16x8*)(Pw + lr * 72 + ks2 * 32 + (lq << 3));
#pragma unroll
      for (int nd = 0; nd < 8; ++nd) {
        int d = nd * 16 + lr;
        bf16x8 vf = *(const bf16x8*)(Vtile + (d << 6) + (((ks2 * 4 + lq) ^ (d & 7)) << 3));
        o[nd] = __builtin_amdgcn_mfma_f32_16x16x32_bf16(pf, vf, o[nd], 0, 0, 0);
      }
    }
  }

  float inv[4];
#pragma unroll
  for (int r = 0; r < 4; ++r) inv[r] = 1.0f / ll[r];
  const int rowb = b * 512 + qb * 64 + w * 16 + lq * 4;
  const int colb = h * 128 + lr;
#pragma unroll
  for (int nd = 0; nd < 8; ++nd)
#pragma unroll
    for (int r = 0; r < 4; ++r)
      Oh[(size_t)(rowb + r) * 2048 + colb + nd * 16] = f2bf(o[nd][r] * inv[r]);
}

// ---------------------------------------------------------------------------
extern "C" void kernel_launch(void* const* d_in, const int* in_sizes, int n_in,
                              void* d_out, int out_size, void* d_ws, size_t ws_size,
                              hipStream_t stream) {
  const float* x  = (const float*)d_in[0];
  const float* wq = (const float*)d_in[1];
  const float* wk = (const float*)d_in[2];
  const float* wv = (const float*)d_in[3];
  const float* wo = (const float*)d_in[4];
  float* out = (float*)d_out;
  char* ws = (char*)d_ws;

  us*    xb   = (us*)(ws);                    // [4096][2048] bf16      16 MB
  us*    wcat = (us*)(ws + 16777216);         // [3072][2048] bf16      12 MB
  us*    wot  = (us*)(ws + 29360128);         // [2048][2048] bf16       8 MB
  us*    Qh   = (us*)(ws + 37748736);         // [128][512][128] bf16   16 MB
  us*    Kh   = (us*)(ws + 54525952);         // [32][512][128] bf16     4 MB
  us*    Vt   = (us*)(ws + 58720256);         // [32][128][512] bf16     4 MB
  us*    Oh   = (us*)(ws + 67108864);         // [4096][2048] bf16      16 MB
  float* ct   = (float*)(ws + 83886080);      // [512][64] fp32
  float* st   = (float*)(ws + 84017152);      // [512][64] fp32

  prep_kernel<<<6784, 256, 0, stream>>>(x, wq, wk, wv, wo, xb, wcat, wot, ct, st);
  gemm_qkv2_kernel<<<768, 256, 0, stream>>>(xb, wcat, Qh, Kh, Vt);
  rope_k_kernel<<<1024, 256, 0, stream>>>(Kh, ct, st);
  attn_kernel<<<1024, 256, 0, stream>>>(Qh, Kh, Vt, Oh, ct, st);
  gemm_out8_kernel<<<256, 512, 0, stream>>>(Oh, wot, out);
}

// Round 9
// 150.136 us; speedup vs baseline: 1.5401x; 1.5401x over previous
//
#include <hip/hip_runtime.h>
#include <hip/hip_bf16.h>
#include <stdint.h>

// ---------------------------------------------------------------------------
// GQA attention block, MI355X/gfx950, bf16 MFMA pipeline.
//   B=8 T=512 C=2048 H=16 KVH=4 D=128
// Round 9: round-6 config (best measured: 150.5 us) + attn upgraded to a
// 2-phase software pipeline: double-buffered K/V tiles, stage j+1 issued
// right after the j-ready fence, one vmcnt(0)+barrier per tile, setprio
// around MFMA clusters. GEMMs/prep/rope identical to round 6.
// ---------------------------------------------------------------------------

typedef __bf16 bf16x8 __attribute__((ext_vector_type(8)));
typedef float  f32x4  __attribute__((ext_vector_type(4)));
typedef float  f4     __attribute__((ext_vector_type(4)));
typedef unsigned short u16x8 __attribute__((ext_vector_type(8)));
typedef unsigned short u16x4 __attribute__((ext_vector_type(4)));
typedef unsigned short us;

template<int V> struct Ic { static constexpr int v = V; };

__device__ __forceinline__ float bf2f(us u) {
  unsigned int x = ((unsigned int)u) << 16;
  return __builtin_bit_cast(float, x);
}
__device__ __forceinline__ us f2bf(float f) {   // round-to-nearest-even
  unsigned int x = __builtin_bit_cast(unsigned int, f);
  unsigned int r = x + 0x7fffu + ((x >> 16) & 1u);
  return (us)(r >> 16);
}

// async global->LDS, 16B per lane; LDS dest must be linear (uniform + lane*16)
__device__ __forceinline__ void gload16(const void* gsrc, void* ldst) {
  auto g = (const __attribute__((address_space(1))) void*)gsrc;
  auto l = (__attribute__((address_space(3))) void*)ldst;
  __builtin_amdgcn_global_load_lds(g, l, 16, 0, 0);
}

#define BAR() __builtin_amdgcn_s_barrier()
#define LGK0() do { asm volatile("s_waitcnt lgkmcnt(0)" ::: "memory"); \
                    __builtin_amdgcn_sched_barrier(0); } while (0)

template<int N> __device__ __forceinline__ void VMW() {
  if constexpr (N == 0)      asm volatile("s_waitcnt vmcnt(0)" ::: "memory");
  else if constexpr (N == 2) asm volatile("s_waitcnt vmcnt(2)" ::: "memory");
  else if constexpr (N == 3) asm volatile("s_waitcnt vmcnt(3)" ::: "memory");
  else if constexpr (N == 4) asm volatile("s_waitcnt vmcnt(4)" ::: "memory");
  else static_assert(N == 0 || N == 2 || N == 3 || N == 4, "unsupported vmcnt");
  __builtin_amdgcn_sched_barrier(0);
}

// ---------------------------------------------------------------------------
// merged prep kernel: grid 6784 x 256
// ---------------------------------------------------------------------------
__global__ __launch_bounds__(256) void prep_kernel(
    const float* __restrict__ x, const float* __restrict__ wq,
    const float* __restrict__ wk, const float* __restrict__ wv,
    const float* __restrict__ wo, us* __restrict__ xb,
    us* __restrict__ wcat, us* __restrict__ wot,
    float* __restrict__ ct, float* __restrict__ st) {
  const int bid = blockIdx.x, tid = threadIdx.x;
  if (bid < 4096) {
    size_t idx = (size_t)bid * 256 + tid;
    const f4* p = (const f4*)(x + idx * 8);
    f4 a = p[0], b = p[1];
    u16x8 o;
#pragma unroll
    for (int e = 0; e < 4; ++e) { o[e] = f2bf(a[e]); o[4 + e] = f2bf(b[e]); }
    *(u16x8*)(xb + idx * 8) = o;
  } else if (bid < 6656) {
    __shared__ float lds[64][65];
    int lb = bid - 4096;              // 0..2559
    int bx = lb % 80, ky = lb / 80;   // ky 0..31
    const float* src; us* dst; int N, rowOff, nb;
    if (bx < 32)      { src = wq; dst = wcat; N = 2048; rowOff = 0;    nb = bx; }
    else if (bx < 40) { src = wk; dst = wcat; N = 512;  rowOff = 2048; nb = bx - 32; }
    else if (bx < 48) { src = wv; dst = wcat; N = 512;  rowOff = 2560; nb = bx - 40; }
    else              { src = wo; dst = wot;  N = 2048; rowOff = 0;    nb = bx - 48; }
    const int n0 = nb * 64, k0 = ky * 64;
    const int c = tid & 63, rq = tid >> 6;
#pragma unroll
    for (int i = 0; i < 16; ++i) {
      int r = i * 4 + rq;
      lds[r][c] = src[(size_t)(k0 + r) * N + n0 + c];
    }
    __syncthreads();
#pragma unroll
    for (int i = 0; i < 16; ++i) {
      int nr = i * 4 + rq;
      dst[(size_t)(rowOff + n0 + nr) * 2048 + k0 + c] = f2bf(lds[c][nr]);
    }
  } else {
    int idx = (bid - 6656) * 256 + tid;   // 0..32767
    int i = idx & 63, t = idx >> 6;
    float inv = exp2f(-(float)i * (13.287712379549449f / 64.0f));
    float ang = (float)t * inv;
    ct[idx] = cosf(ang);
    st[idx] = sinf(ang);
  }
}

// in-place RoPE on Kh [32][512][128] only (Q roped in attn). grid 1024.
__global__ void rope_k_kernel(us* __restrict__ Kh,
                              const float* __restrict__ ct, const float* __restrict__ st) {
  int idx = blockIdx.x * 256 + threadIdx.x;   // 262,144 exact
  int dq = idx & 15;
  int t = (idx >> 4) & 511;
  int slot = idx >> 13;                       // 0..31
  us* rowp = Kh + ((size_t)slot * 512 + t) * 128;
  int d0 = dq * 4;
  u16x4 x1 = *(const u16x4*)(rowp + d0);
  u16x4 x2 = *(const u16x4*)(rowp + 64 + d0);
  f4 c = *(const f4*)(ct + t * 64 + d0);
  f4 s = *(const f4*)(st + t * 64 + d0);
  u16x4 o1, o2;
#pragma unroll
  for (int e = 0; e < 4; ++e) {
    float a = bf2f(x1[e]), b = bf2f(x2[e]);
    o1[e] = f2bf(a * c[e] - b * s[e]);
    o2[e] = f2bf(b * c[e] + a * s[e]);
  }
  *(u16x4*)(rowp + d0) = o1;
  *(u16x4*)(rowp + 64 + d0) = o2;
}

// ---------------------------------------------------------------------------
// m97-style 2-phase 128x128 GEMM core (3 blocks/CU). XOR-swizzled LDS.
// (round-6 verified winner: 68.6 us / 751 TF on qkv)
// ---------------------------------------------------------------------------
__device__ __forceinline__ void gemm2_core(const us* __restrict__ A,
    const us* __restrict__ Bt, const int K, const int m0, const int n0,
    us* AT, us* BT, f32x4 (&acc)[4][4]) {
  const int tid = threadIdx.x;
  const int lane = tid & 63;
  const int wid = tid >> 6;
  const int wm = wid >> 1, wn = wid & 1;
  const int lr = lane & 15, lq = lane >> 4;
  const f32x4 zz = {0.f, 0.f, 0.f, 0.f};
#pragma unroll
  for (int i = 0; i < 4; ++i)
#pragma unroll
    for (int j = 0; j < 4; ++j) acc[i][j] = zz;

  const int KT = K >> 6;
  for (int kt = 0; kt < KT; ++kt) {
    __syncthreads();
#pragma unroll
    for (int i = 0; i < 4; ++i) {
      int c = i * 256 + tid;
      int row = c >> 3, kc = (c & 7) ^ (row & 7);
      gload16(A + (size_t)(m0 + row) * K + (kt << 6) + (kc << 3), AT + c * 8);
    }
#pragma unroll
    for (int i = 0; i < 4; ++i) {
      int c = i * 256 + tid;
      int row = c >> 3, kc = (c & 7) ^ (row & 7);
      gload16(Bt + (size_t)(n0 + row) * K + (kt << 6) + (kc << 3), BT + c * 8);
    }
    __syncthreads();
#pragma unroll
    for (int ks = 0; ks < 2; ++ks) {
      bf16x8 af[4], bfm[4];
#pragma unroll
      for (int i = 0; i < 4; ++i) {
        int R = wm * 64 + i * 16 + lr;
        af[i] = *(const bf16x8*)((const char*)AT + R * 128 +
                                 ((ks * 64 + lq * 16) ^ ((R & 7) << 4)));
      }
#pragma unroll
      for (int j = 0; j < 4; ++j) {
        int R = wn * 64 + j * 16 + lr;
        bfm[j] = *(const bf16x8*)((const char*)BT + R * 128 +
                                  ((ks * 64 + lq * 16) ^ ((R & 7) << 4)));
      }
#pragma unroll
      for (int i = 0; i < 4; ++i)
#pragma unroll
        for (int j = 0; j < 4; ++j)
          acc[i][j] = __builtin_amdgcn_mfma_f32_16x16x32_bf16(af[i], bfm[j], acc[i][j], 0, 0, 0);
    }
  }
}

// QKV GEMM: xb [4096][2048] @ wcat [3072][2048]^T; Q,K scattered per-head,
// V scattered directly transposed into Vt [32][128][512].
// XCD chunk = 4 m-tiles x 24 n-tiles: A panels (2 MB) stay L2-resident.
__global__ __launch_bounds__(256, 4) void gemm_qkv2_kernel(const us* __restrict__ xb,
    const us* __restrict__ wcat, us* __restrict__ Qh, us* __restrict__ Kh,
    us* __restrict__ Vt) {
  __shared__ __align__(16) us AT[128 * 64];
  __shared__ __align__(16) us BT[128 * 64];
  const int bid = blockIdx.x;                     // 768 = 8 XCD * 96
  const int xcd = bid & 7, c = bid >> 3;          // c in [0,96)
  const int m0 = (xcd * 4 + c / 24) << 7;         // 4 A-panels per XCD
  const int n0 = (c % 24) << 7;                   // n fastest: 24 co-resident
  f32x4 acc[4][4];
  gemm2_core(xb, wcat, 2048, m0, n0, AT, BT, acc);

  const int tid = threadIdx.x, lane = tid & 63, wid = tid >> 6;
  const int wm = wid >> 1, wn = wid & 1, lr = lane & 15, lq = lane >> 4;
#pragma unroll
  for (int i = 0; i < 4; ++i)
#pragma unroll
    for (int j = 0; j < 4; ++j) {
      int col = n0 + wn * 64 + j * 16 + lr;
#pragma unroll
      for (int r = 0; r < 4; ++r) {
        int row = m0 + wm * 64 + i * 16 + lq * 4 + r;
        int bb = row >> 9, t = row & 511;
        us val = f2bf(acc[i][j][r]);
        if (col < 2048) {
          Qh[((size_t)(bb * 16 + (col >> 7)) * 512 + t) * 128 + (col & 127)] = val;
        } else if (col < 2560) {
          int cc = col - 2048;
          Kh[((size_t)(bb * 4 + (cc >> 7)) * 512 + t) * 128 + (cc & 127)] = val;
        } else {
          int cc = col - 2560;
          Vt[((size_t)(bb * 4 + (cc >> 7)) * 128 + (cc & 127)) * 512 + t] = val;
        }
      }
    }
}

// ---------------------------------------------------------------------------
// 8-phase counted-vmcnt GEMM core (round-5/6 version): out-GEMM only.
// ---------------------------------------------------------------------------
template<int BM, int BN, int WM, int WN>
__device__ __forceinline__ void gemm8_core(const us* __restrict__ A,
    const us* __restrict__ Bt, const int K, const int m0, const int n0,
    us* sm, f32x4 (&acc)[BM / (16 * WM)][BN / (16 * WN)]) {
  constexpr int MF = BM / (16 * WM), NF = BN / (16 * WN);
  constexpr int MH = MF / 2, NH = NF / 2;
  constexpr int QM = MH * 16, QN = NH * 16;     // per-wave quarter rows
  constexpr int AHALF = (BM / 2) * 64, ABUF = BM * 64, ALDS = 2 * ABUF;
  constexpr int BHALF = (BN / 2) * 64, BBUF = BN * 64;
  constexpr int AL = BM / 128, BL = BN / 128;   // gloads/thread per half
  const int tid = threadIdx.x, lane = tid & 63, wid = tid >> 6;
  const int wm = wid / WN, wn = wid % WN;
  const int lr = lane & 15, lq = lane >> 4;

  const f32x4 zz = {0.f, 0.f, 0.f, 0.f};
#pragma unroll
  for (int i = 0; i < MF; ++i)
#pragma unroll
    for (int j = 0; j < NF; ++j) acc[i][j] = zz;

  bf16x8 afr[MH][2], bfr[NH][2];

  auto stageA = [&](int kt, int qd, int h) {
#pragma unroll
    for (int i = 0; i < AL; ++i) {
      int c = i * 512 + tid;
      int lrow = c >> 3;
      int grow = (lrow / QM) * (2 * QM) + h * QM + (lrow % QM);
      int kcs = (c & 7) ^ (lrow & 7);
      gload16(A + (size_t)(m0 + grow) * K + (kt << 6) + (kcs << 3),
              sm + qd * ABUF + h * AHALF + c * 8);
    }
  };
  auto stageB = [&](int kt, int qd, int h) {
#pragma unroll
    for (int i = 0; i < BL; ++i) {
      int c = i * 512 + tid;
      int lrow = c >> 3;
      int grow = (lrow / QN) * (2 * QN) + h * QN + (lrow % QN);
      int kcs = (c & 7) ^ (lrow & 7);
      gload16(Bt + (size_t)(n0 + grow) * K + (kt << 6) + (kcs << 3),
              sm + ALDS + qd * BBUF + h * BHALF + c * 8);
    }
  };
  auto lda = [&](int q, int h) {
#pragma unroll
    for (int f = 0; f < MH; ++f) {
      int R = wm * QM + f * 16 + lr;
      const char* base = (const char*)(sm + q * ABUF + h * AHALF + R * 64);
      int sw = (R & 7) << 4;
#pragma unroll
      for (int ks = 0; ks < 2; ++ks)
        afr[f][ks] = *(const bf16x8*)(base + ((ks * 64 + lq * 16) ^ sw));
    }
  };
  auto ldb = [&](int q, int h) {
#pragma unroll
    for (int g = 0; g < NH; ++g) {
      int R = wn * QN + g * 16 + lr;
      const char* base = (const char*)(sm + ALDS + q * BBUF + h * BHALF + R * 64);
      int sw = (R & 7) << 4;
#pragma unroll
      for (int ks = 0; ks < 2; ++ks)
        bfr[g][ks] = *(const bf16x8*)(base + ((ks * 64 + lq * 16) ^ sw));
    }
  };
  auto mmac = [&](auto MQ, auto NQ) {
    constexpr int mq = decltype(MQ)::v, nq = decltype(NQ)::v;
    __builtin_amdgcn_s_setprio(1);
#pragma unroll
    for (int ks = 0; ks < 2; ++ks)
#pragma unroll
      for (int f = 0; f < MH; ++f)
#pragma unroll
        for (int g = 0; g < NH; ++g)
          acc[mq * MH + f][nq * NH + g] = __builtin_amdgcn_mfma_f32_16x16x32_bf16(
              afr[f][ks], bfr[g][ks], acc[mq * MH + f][nq * NH + g], 0, 0, 0);
    __builtin_amdgcn_s_setprio(0);
  };

  // prologue: tile 0 -> buf 0, issue order = consumption order
  stageA(0, 0, 0); stageB(0, 0, 0); stageB(0, 0, 1); stageA(0, 0, 1);
  VMW<AL + BL>(); BAR();

  const int NT = K >> 6;
  for (int kt = 0; kt < NT; ++kt) {
    const int q = kt & 1, qn = q ^ 1;
    const bool pf = (kt + 1 < NT);
    // ---- ph1: quadrant (0,0); reads Ah0,Bh0 ----
    lda(q, 0); ldb(q, 0);
    if (pf) stageA(kt + 1, qn, 0);
    BAR(); LGK0(); mmac(Ic<0>{}, Ic<0>{});
    if (pf) VMW<2 * AL>(); else VMW<AL>();       // next: Bh1(kt)
    BAR();
    // ---- ph2: quadrant (0,1); reads Bh1 ----
    ldb(q, 1);
    if (pf) stageB(kt + 1, qn, 0);
    BAR(); LGK0(); mmac(Ic<0>{}, Ic<1>{});
    if (pf) VMW<AL + BL>(); else VMW<0>();       // next: Ah1(kt)
    BAR();
    // ---- ph3: quadrant (1,1); reads Ah1 ----
    lda(q, 1);
    if (pf) stageB(kt + 1, qn, 1);
    BAR(); LGK0(); mmac(Ic<1>{}, Ic<1>{});
    BAR();                                        // ph4 needs nothing new
    // ---- ph4: quadrant (1,0); re-reads Bh0 ----
    ldb(q, 0);
    if (pf) stageA(kt + 1, qn, 1);
    BAR(); LGK0(); mmac(Ic<1>{}, Ic<0>{});
    if (pf) VMW<AL + BL>();                      // next tile: Ah0,Bh0(kt+1)
    BAR();
  }
}

// output GEMM: Oh [4096][2048] @ wot [2048][2048]^T -> fp32 out, 256x128 tiles
// XCD chunk = 2 m-tiles x 16 n-tiles: A panels (2 MB) L2-resident, B streamed.
__global__ __launch_bounds__(512, 2) void gemm_out8_kernel(const us* __restrict__ Ob,
    const us* __restrict__ wot, float* __restrict__ out) {
  __shared__ __align__(16) us sm[49152];          // 96 KiB
  const int bid = blockIdx.x;                     // 256 = 8 XCD * 32
  const int xcd = bid & 7, c = bid >> 3;          // c in [0,32)
  const int m0 = (xcd * 2 + (c >> 4)) << 8;       // 2 A-panels per XCD
  const int n0 = (c & 15) << 7;                   // n fastest: 16 co-resident
  f32x4 acc[8][2];
  gemm8_core<256, 128, 2, 4>(Ob, wot, 2048, m0, n0, sm, acc);

  const int tid = threadIdx.x, lane = tid & 63, wid = tid >> 6;
  const int wm = wid >> 2, wn = wid & 3, lr = lane & 15, lq = lane >> 4;
#pragma unroll
  for (int f = 0; f < 8; ++f)
#pragma unroll
    for (int g = 0; g < 2; ++g) {
      int col = n0 + wn * 32 + g * 16 + lr;
#pragma unroll
      for (int r = 0; r < 4; ++r) {
        int row = m0 + wm * 128 + f * 16 + lq * 4 + r;
        out[(size_t)row * 2048 + col] = acc[f][g][r];
      }
    }
}

// ---------------------------------------------------------------------------
// flash attention, 2-phase pipelined K/V staging (double-buffered LDS):
//   per tile j: [vmcnt(0); barrier]  -> tile j resident
//               stage tile j+1 into the dead buffer (8 gload16/thread)
//               compute QK^T -> softmax -> PV on tile j
// One vmcnt + one barrier per tile; staging hides under ~600+ cyc compute.
// Grid 1024: xcd = batch b (K/V+Q L2-resident), qb reversed (LPT).
// In-register Q-RoPE+scale. setprio(1) around MFMA clusters.
// ---------------------------------------------------------------------------
__global__ __launch_bounds__(256) void attn_kernel(const us* __restrict__ Qh,
    const us* __restrict__ Kh, const us* __restrict__ Vt, us* __restrict__ Oh,
    const float* __restrict__ ct, const float* __restrict__ st) {
  __shared__ __align__(16) us Ktile[2][64 * 128];   // 2 x 16 KiB
  __shared__ __align__(16) us Vtile[2][128 * 64];   // 2 x 16 KiB
  __shared__ __align__(16) us Plds[4 * 16 * 72];    // 9 KiB
  const int tid = threadIdx.x, lane = tid & 63, w = tid >> 6;
  const int lr = lane & 15, lq = lane >> 4;
  const int bid = blockIdx.x;            // 1024 = 8 XCD(=batch) * 128
  const int b = bid & 7, cc_ = bid >> 3; // cc_ in [0,128)
  const int h = cc_ & 15, qb = 7 - (cc_ >> 4);
  const int bh = b * 16 + h, kvh = h >> 2;
  const us* Kbh = Kh + (size_t)(b * 4 + kvh) * 512 * 128;
  const us* Vbh = Vt + (size_t)(b * 4 + kvh) * 128 * 512;

  auto stageK = [&](int j, int buf) {
#pragma unroll
    for (int it = 0; it < 4; ++it) {
      int c = it * 256 + tid;
      int row = c >> 4, kc = c & 15;
      gload16(Kbh + (size_t)(j * 64 + row) * 128 + ((kc ^ (row & 7)) << 3),
              Ktile[buf] + (c << 3));
    }
  };
  auto stageV = [&](int j, int buf) {
#pragma unroll
    for (int it = 0; it < 4; ++it) {
      int c = it * 256 + tid;
      int row = c >> 3, tc = c & 7;
      gload16(Vbh + (size_t)row * 512 + j * 64 + ((tc ^ (row & 7)) << 3),
              Vtile[buf] + (c << 3));
    }
  };

  // Q fragments with in-register RoPE + 1/sqrt(128) scale.
  const int t_abs = qb * 64 + w * 16 + lr;
  const us* Qrow = Qh + ((size_t)bh * 512 + t_abs) * 128;
  bf16x8 qf[4];
  {
    const float* cp = ct + t_abs * 64 + (lq << 3);
    const float* sp = st + t_abs * 64 + (lq << 3);
#pragma unroll
    for (int ks = 0; ks < 2; ++ks) {
      u16x8 a = *(const u16x8*)(Qrow + ks * 32 + (lq << 3));
      u16x8 bb2 = *(const u16x8*)(Qrow + 64 + ks * 32 + (lq << 3));
      u16x8 oa, ob;
#pragma unroll
      for (int e = 0; e < 8; ++e) {
        float c = cp[ks * 32 + e], s = sp[ks * 32 + e];
        float av = bf2f(a[e]), bv = bf2f(bb2[e]);
        oa[e] = f2bf((av * c - bv * s) * 0.08838834764831845f);
        ob[e] = f2bf((bv * c + av * s) * 0.08838834764831845f);
      }
      qf[ks] = __builtin_bit_cast(bf16x8, oa);
      qf[ks + 2] = __builtin_bit_cast(bf16x8, ob);
    }
  }

  const f32x4 zz = {0.f, 0.f, 0.f, 0.f};
  f32x4 o[8];
#pragma unroll
  for (int i = 0; i < 8; ++i) o[i] = zz;
  float m[4], ll[4];
#pragma unroll
  for (int r = 0; r < 4; ++r) { m[r] = -1e30f; ll[r] = 0.f; }
  us* Pw = Plds + w * 16 * 72;

  // prologue: stage tile 0 into buf 0
  stageK(0, 0); stageV(0, 0);

  for (int j = 0; j <= qb; ++j) {
    const int cur = j & 1;
    VMW<0>();            // own stage loads for tile j complete
    BAR();               // everyone's loads landed; buf[cur^1] readers done
    if (j < qb) { stageK(j + 1, cur ^ 1); stageV(j + 1, cur ^ 1); }

    const us* Kt = Ktile[cur];
    const us* Vtl = Vtile[cur];

    f32x4 s[4];
#pragma unroll
    for (int nb = 0; nb < 4; ++nb) s[nb] = zz;
    __builtin_amdgcn_s_setprio(1);
#pragma unroll
    for (int ks = 0; ks < 4; ++ks) {
#pragma unroll
      for (int nb = 0; nb < 4; ++nb) {
        int row = nb * 16 + lr;
        bf16x8 kf = *(const bf16x8*)(Kt + (row << 7) + (((ks * 4 + lq) ^ (row & 7)) << 3));
        s[nb] = __builtin_amdgcn_mfma_f32_16x16x32_bf16(qf[ks], kf, s[nb], 0, 0, 0);
      }
    }
    __builtin_amdgcn_s_setprio(0);
    if (j == qb) {   // causal mask on the diagonal tile
#pragma unroll
      for (int nb = 0; nb < 4; ++nb)
#pragma unroll
        for (int r = 0; r < 4; ++r)
          if (nb * 16 + lr > w * 16 + lq * 4 + r) s[nb][r] = -1e30f;
    }

    float tm[4], alpha[4], rs[4];
#pragma unroll
    for (int r = 0; r < 4; ++r)
      tm[r] = fmaxf(fmaxf(s[0][r], s[1][r]), fmaxf(s[2][r], s[3][r]));
#pragma unroll
    for (int off = 1; off < 16; off <<= 1)
#pragma unroll
      for (int r = 0; r < 4; ++r)
        tm[r] = fmaxf(tm[r], __shfl_xor(tm[r], off, 64));
#pragma unroll
    for (int r = 0; r < 4; ++r) {
      float mn = fmaxf(m[r], tm[r]);
      alpha[r] = __expf(m[r] - mn);
      m[r] = mn;
    }
#pragma unroll
    for (int nb = 0; nb < 4; ++nb)
#pragma unroll
      for (int r = 0; r < 4; ++r)
        s[nb][r] = __expf(s[nb][r] - m[r]);
#pragma unroll
    for (int r = 0; r < 4; ++r)
      rs[r] = s[0][r] + s[1][r] + s[2][r] + s[3][r];
#pragma unroll
    for (int off = 1; off < 16; off <<= 1)
#pragma unroll
      for (int r = 0; r < 4; ++r)
        rs[r] += __shfl_xor(rs[r], off, 64);
#pragma unroll
    for (int r = 0; r < 4; ++r) ll[r] = ll[r] * alpha[r] + rs[r];
#pragma unroll
    for (int i = 0; i < 8; ++i)
#pragma unroll
      for (int r = 0; r < 4; ++r) o[i][r] *= alpha[r];

    // P (C layout) -> per-wave LDS -> re-read in A layout (same wave)
#pragma unroll
    for (int nb = 0; nb < 4; ++nb)
#pragma unroll
      for (int r = 0; r < 4; ++r)
        Pw[(lq * 4 + r) * 72 + nb * 16 + lr] = f2bf(s[nb][r]);

#pragma unroll
    for (int ks2 = 0; ks2 < 2; ++ks2) {
      bf16x8 pf = *(const bf16x8*)(Pw + lr * 72 + ks2 * 32 + (lq << 3));
      __builtin_amdgcn_s_setprio(1);
#pragma unroll
      for (int nd = 0; nd < 8; ++nd) {
        int d = nd * 16 + lr;
        bf16x8 vf = *(const bf16x8*)(Vtl + (d << 6) + (((ks2 * 4 + lq) ^ (d & 7)) << 3));
        o[nd] = __builtin_amdgcn_mfma_f32_16x16x32_bf16(pf, vf, o[nd], 0, 0, 0);
      }
      __builtin_amdgcn_s_setprio(0);
    }
  }

  float inv[4];
#pragma unroll
  for (int r = 0; r < 4; ++r) inv[r] = 1.0f / ll[r];
  const int rowb = b * 512 + qb * 64 + w * 16 + lq * 4;
  const int colb = h * 128 + lr;
#pragma unroll
  for (int nd = 0; nd < 8; ++nd)
#pragma unroll
    for (int r = 0; r < 4; ++r)
      Oh[(size_t)(rowb + r) * 2048 + colb + nd * 16] = f2bf(o[nd][r] * inv[r]);
}

// ---------------------------------------------------------------------------
extern "C" void kernel_launch(void* const* d_in, const int* in_sizes, int n_in,
                              void* d_out, int out_size, void* d_ws, size_t ws_size,
                              hipStream_t stream) {
  const float* x  = (const float*)d_in[0];
  const float* wq = (const float*)d_in[1];
  const float* wk = (const float*)d_in[2];
  const float* wv = (const float*)d_in[3];
  const float* wo = (const float*)d_in[4];
  float* out = (float*)d_out;
  char* ws = (char*)d_ws;

  us*    xb   = (us*)(ws);                    // [4096][2048] bf16      16 MB
  us*    wcat = (us*)(ws + 16777216);         // [3072][2048] bf16      12 MB
  us*    wot  = (us*)(ws + 29360128);         // [2048][2048] bf16       8 MB
  us*    Qh   = (us*)(ws + 37748736);         // [128][512][128] bf16   16 MB
  us*    Kh   = (us*)(ws + 54525952);         // [32][512][128] bf16     4 MB
  us*    Vt   = (us*)(ws + 58720256);         // [32][128][512] bf16     4 MB
  us*    Oh   = (us*)(ws + 67108864);         // [4096][2048] bf16      16 MB
  float* ct   = (float*)(ws + 83886080);      // [512][64] fp32
  float* st   = (float*)(ws + 84017152);      // [512][64] fp32

  prep_kernel<<<6784, 256, 0, stream>>>(x, wq, wk, wv, wo, xb, wcat, wot, ct, st);
  gemm_qkv2_kernel<<<768, 256, 0, stream>>>(xb, wcat, Qh, Kh, Vt);
  rope_k_kernel<<<1024, 256, 0, stream>>>(Kh, ct, st);
  attn_kernel<<<1024, 256, 0, stream>>>(Qh, Kh, Vt, Oh, ct, st);
  gemm_out8_kernel<<<256, 512, 0, stream>>>(Oh, wot, out);
}